// Round 10
// baseline (141.182 us; speedup 1.0000x reference)
//
#include <hip/hip_runtime.h>
#include <hip/hip_bf16.h>

#define NTOT   8192
#define BHALF  4096
#define DDIM   256
#define NPART  4      // partial copies of s_part to spread atomic contention
#define MAXSLOT 34    // strips per wave across both phases: <= 32 + 1 (+1 slack)
#define EXPSCALE 14.4269504088896341f   // 10 / ln(2): exp(10x) = exp2(EXPSCALE*x)

typedef __attribute__((ext_vector_type(8))) short bf16x8_t;  // 8 bf16 = 4 VGPRs
typedef __attribute__((ext_vector_type(4))) float f32x4_t;   // MFMA C/D

__device__ inline unsigned short f2bf(float x) {
    __hip_bfloat16 h = __float2bfloat16(x);
    return __builtin_bit_cast(unsigned short, h);
}

// ---- kernel 1: normalize pair k (rows k, k+B) -> bf16 zn; posdot; zero s_part ----
__global__ void norm_pair_kernel(const float* __restrict__ zi,
                                 const float* __restrict__ zj,
                                 unsigned short* __restrict__ zn,
                                 float* __restrict__ posdot,
                                 float* __restrict__ s_part) {
    int gtid = blockIdx.x * 256 + threadIdx.x;
    if (gtid < NTOT * NPART) s_part[gtid] = 0.0f;   // done before gemm (stream order)
    int k    = gtid >> 6;
    int lane = gtid & 63;
    float4 vi = reinterpret_cast<const float4*>(zi + (size_t)k * DDIM)[lane];
    float4 vj = reinterpret_cast<const float4*>(zj + (size_t)k * DDIM)[lane];
    float ssi = vi.x*vi.x + vi.y*vi.y + vi.z*vi.z + vi.w*vi.w;
    float ssj = vj.x*vj.x + vj.y*vj.y + vj.z*vj.z + vj.w*vj.w;
    float dot = vi.x*vj.x + vi.y*vj.y + vi.z*vj.z + vi.w*vj.w;
    #pragma unroll
    for (int off = 32; off >= 1; off >>= 1) {
        ssi += __shfl_xor(ssi, off);
        ssj += __shfl_xor(ssj, off);
        dot += __shfl_xor(dot, off);
    }
    float ri = 1.0f / fmaxf(sqrtf(ssi), 1e-8f);
    float rj = 1.0f / fmaxf(sqrtf(ssj), 1e-8f);
    ushort4 oi, oj;
    oi.x = f2bf(vi.x * ri); oi.y = f2bf(vi.y * ri);
    oi.z = f2bf(vi.z * ri); oi.w = f2bf(vi.w * ri);
    oj.x = f2bf(vj.x * rj); oj.y = f2bf(vj.y * rj);
    oj.z = f2bf(vj.z * rj); oj.w = f2bf(vj.w * rj);
    reinterpret_cast<ushort4*>(zn + (size_t)k * DDIM)[lane] = oi;
    reinterpret_cast<ushort4*>(zn + (size_t)(k + BHALF) * DDIM)[lane] = oj;
    if (lane == 0) posdot[k] = dot * ri * rj * 10.0f;
}

// ---- kernel 2: symmetric fused GEMM + exp-sum, v10: v5 minus its two poisons ----
// (resubmission -- round 9 bench was an infra failure, no data)
// v9 confirmed the 4-domain cell is allocator-infeasible (128-reg budget <
// working set -> 50MB spills). Back to the barrier-free reg-streaming branch:
// v5's 74us was caused by (a) per-strip atomicAdd in the vmcnt queue -- in-order
// retirement made every strip's B-load wait ~600cy for the atomic to reach the
// coherent point -- and (b) the compiler SINKING each B-load to its MFMA use
// (VGPR_Count=100 proves b0/b1 were never held), collapsing the pipeline.
// v10: (1) colsums buffered in per-wave LDS slots (no cross-wave sharing -> no
// barriers; flushed once at end); NO atomics anywhere in the loop. (2)
// sched_barrier(0) after every LOADB pins issue order: strip i+1's 8 loads
// issue before strip i's MFMAs; compiler's auto-waitcnt becomes a counted
// vmcnt(8). (3) opaque-asm keeps A resident; waves_per_eu(2,2) = 256-reg
// budget, 8 waves/CU. Zero barriers, zero staging LDS, waves free-drift.
__global__ void __attribute__((amdgpu_flat_work_group_size(256, 256),
                               amdgpu_waves_per_eu(2, 2)))
gemm_sym_kernel(const unsigned short* __restrict__ zn,
                float* __restrict__ s_part) {
    __shared__ float colLDS[4][MAXSLOT][16];   // 8.5 KB, per-wave slot regions

    const int tid  = threadIdx.x;
    const int lane = tid & 63;
    const int wv   = tid >> 6;
    const int m    = lane & 15;
    const int quad = lane >> 4;
    const int wid  = blockIdx.x * 4 + wv;   // 0..2047
    const int p    = wid >> 4;              // pair index 0..127
    const int j    = wid & 15;              // residue lane 0..15

    float* rowPart = s_part + (size_t)(j & (NPART - 1)) * NTOT;
    float* colPart = s_part + (size_t)(p & (NPART - 1)) * NTOT;

// load B fragments for 16-col strip Cs: cols Cs*16+m, k = kk*32+quad*8 (+0..7)
#define LOADB(dst, Cs) {                                                      \
    const unsigned short* bp_ = zn + (size_t)(Cs) * (16 * DDIM)               \
                                + (size_t)m * DDIM + quad * 8;                \
    _Pragma("unroll")                                                         \
    for (int kk_ = 0; kk_ < 8; ++kk_)                                         \
        dst[kk_] = *reinterpret_cast<const bf16x8_t*>(bp_ + kk_ * 32); }

// 16 MFMAs (4 independent chains) + fused exp/rowsum/colsum epilogue.
// colsum goes to this wave's LDS slot -- NO atomics in the loop.
#define COMPUTE(buf, Cs) {                                                    \
    const bool diag_ = (((Cs) >> 1) == R);                                    \
    f32x4_t az00 = (f32x4_t){0.f,0.f,0.f,0.f};                                \
    f32x4_t az01 = (f32x4_t){0.f,0.f,0.f,0.f};                                \
    f32x4_t az10 = (f32x4_t){0.f,0.f,0.f,0.f};                                \
    f32x4_t az11 = (f32x4_t){0.f,0.f,0.f,0.f};                                \
    _Pragma("unroll")                                                         \
    for (int kk_ = 0; kk_ < 4; ++kk_) {                                       \
        az00 = __builtin_amdgcn_mfma_f32_16x16x32_bf16(afrag[0][kk_],     buf[kk_],     az00, 0, 0, 0); \
        az10 = __builtin_amdgcn_mfma_f32_16x16x32_bf16(afrag[1][kk_],     buf[kk_],     az10, 0, 0, 0); \
        az01 = __builtin_amdgcn_mfma_f32_16x16x32_bf16(afrag[0][kk_ + 4], buf[kk_ + 4], az01, 0, 0, 0); \
        az11 = __builtin_amdgcn_mfma_f32_16x16x32_bf16(afrag[1][kk_ + 4], buf[kk_ + 4], az11, 0, 0, 0); \
    }                                                                         \
    const int gc_ = (Cs) * 16 + m;                                            \
    float colsum_ = 0.f;                                                      \
    _Pragma("unroll")                                                         \
    for (int r_ = 0; r_ < 4; ++r_) {                                          \
        float e0_ = exp2f((az00[r_] + az01[r_]) * EXPSCALE);                  \
        float e1_ = exp2f((az10[r_] + az11[r_]) * EXPSCALE);                  \
        if (diag_) {                                                          \
            int gr_ = (R << 5) + quad * 4 + r_;                               \
            e0_ = (gc_ > gr_)      ? e0_ : 0.f;                               \
            e1_ = (gc_ > gr_ + 16) ? e1_ : 0.f;                               \
        }                                                                     \
        rowacc[0][r_] += e0_;                                                 \
        rowacc[1][r_] += e1_;                                                 \
        colsum_ += e0_ + e1_;                                                 \
    }                                                                         \
    colsum_ += __shfl_xor(colsum_, 16);                                       \
    colsum_ += __shfl_xor(colsum_, 32);                                       \
    if (quad == 0) colLDS[wv][slot][m] = colsum_;                             \
    ++slot; }

    int slot = 0;
    #pragma unroll
    for (int phase = 0; phase < 2; ++phase) {
        const int R  = phase ? (255 - p) : p;   // 32-row tile index 0..255
        const int jj = phase ? (15 - j) : j;    // anti-correlated residue
        const int cb = 2 * R;                   // first 16-col strip with upper cells
        int C = cb + ((jj - cb) & 15);          // first strip ≡ jj (mod 16), >= cb
        if (C >= 512) continue;                 // no strips in this phase

        // A fragments: rows R*32 + rf*16 + m, k = kk*32 + quad*8 (+0..7)
        bf16x8_t afrag[2][8];
        #pragma unroll
        for (int rf = 0; rf < 2; ++rf) {
            const unsigned short* ap =
                zn + (size_t)((R << 5) + rf * 16 + m) * DDIM + quad * 8;
            #pragma unroll
            for (int kk = 0; kk < 8; ++kk)
                afrag[rf][kk] = *reinterpret_cast<const bf16x8_t*>(ap + kk * 32);
        }
        // make A values opaque: compiler cannot rematerialize them from memory
        #pragma unroll
        for (int rf = 0; rf < 2; ++rf)
            #pragma unroll
            for (int kk = 0; kk < 8; ++kk) {
                int4 t_ = __builtin_bit_cast(int4, afrag[rf][kk]);
                asm volatile("" : "+v"(t_.x), "+v"(t_.y), "+v"(t_.z), "+v"(t_.w));
                afrag[rf][kk] = __builtin_bit_cast(bf16x8_t, t_);
            }

        float rowacc[2][4] = {{0.f,0.f,0.f,0.f},{0.f,0.f,0.f,0.f}};

        // static 2-buffer rotation; sched_barrier(0) after each LOADB pins the
        // software pipeline (loads of strip i+1 issue BEFORE strip i's MFMAs)
        bf16x8_t b0[8], b1[8];
        LOADB(b0, C);
        __builtin_amdgcn_sched_barrier(0);
        int Cn = C + 16;
        for (;;) {
            if (Cn < 512) LOADB(b1, Cn);
            __builtin_amdgcn_sched_barrier(0);
            COMPUTE(b0, C);
            C = Cn; Cn += 16;
            if (C >= 512) break;
            if (Cn < 512) LOADB(b0, Cn);
            __builtin_amdgcn_sched_barrier(0);
            COMPUTE(b1, C);
            C = Cn; Cn += 16;
            if (C >= 512) break;
        }

        // row totals: reduce over 16 m-lanes, one atomic per row per phase
        #pragma unroll
        for (int rf = 0; rf < 2; ++rf)
            #pragma unroll
            for (int r = 0; r < 4; ++r) {
                float v = rowacc[rf][r];
                v += __shfl_xor(v, 1);
                v += __shfl_xor(v, 2);
                v += __shfl_xor(v, 4);
                v += __shfl_xor(v, 8);
                if (m == 0)
                    atomicAdd(&rowPart[(R << 5) + rf*16 + quad*4 + r], v);
            }
    }
#undef LOADB
#undef COMPUTE

    // flush column sums: re-enumerate strips in the same order (same wave that
    // wrote reads back -- DS ops in-order within a wave, no barrier needed)
    int slot2 = 0;
    #pragma unroll
    for (int phase = 0; phase < 2; ++phase) {
        const int R  = phase ? (255 - p) : p;
        const int jj = phase ? (15 - j) : j;
        const int cb = 2 * R;
        int C = cb + ((jj - cb) & 15);
        for (; C < 512; C += 16) {
            if (quad == 0) atomicAdd(&colPart[C * 16 + m], colLDS[wv][slot2][m]);
            ++slot2;
        }
    }
}

// ---- kernel 3: loss_k = log(sum_p s_part[p][k]) - posdot[k%B]; masked mean ----
__global__ void finalize_kernel(const float* __restrict__ s_part,
                                const float* __restrict__ posdot,
                                const unsigned char* __restrict__ mask,
                                float* __restrict__ out) {
    int tid = threadIdx.x, lane = tid & 63, wv = tid >> 6;
    float tot = 0.f, cnt = 0.f;
    #pragma unroll
    for (int si = 0; si < NTOT / 1024; ++si) {
        int k = si * 1024 + tid;
        int kb = k & (BHALF - 1);
        if (mask[kb] != 0) {
            float sk = s_part[k] + s_part[NTOT + k]
                     + s_part[2*NTOT + k] + s_part[3*NTOT + k];
            tot += __logf(sk) - posdot[kb];
            cnt += 1.f;
        }
    }
    #pragma unroll
    for (int off = 32; off >= 1; off >>= 1) {
        tot += __shfl_xor(tot, off);
        cnt += __shfl_xor(cnt, off);
    }
    __shared__ float st[16], sc[16];
    if (lane == 0) { st[wv] = tot; sc[wv] = cnt; }
    __syncthreads();
    if (tid == 0) {
        float T = 0.f, C = 0.f;
        #pragma unroll
        for (int i = 0; i < 16; ++i) { T += st[i]; C += sc[i]; }
        out[0] = (C > 0.f) ? (T / fmaxf(C, 1.f)) : 0.f;
    }
}

extern "C" void kernel_launch(void* const* d_in, const int* in_sizes, int n_in,
                              void* d_out, int out_size, void* d_ws, size_t ws_size,
                              hipStream_t stream) {
    const float* zi = (const float*)d_in[0];
    const float* zj = (const float*)d_in[1];
    const unsigned char* mask = (const unsigned char*)d_in[2];
    float* out = (float*)d_out;

    // ws: [0,4MB) zn bf16; s_part[NPART][8192] f32; posdot[4096] f32
    unsigned short* zn = (unsigned short*)d_ws;
    float* s_part = (float*)((char*)d_ws + (size_t)NTOT * DDIM * 2);
    float* posdot = s_part + NPART * NTOT;

    norm_pair_kernel<<<dim3(1024), dim3(256), 0, stream>>>(zi, zj, zn, posdot, s_part);
    gemm_sym_kernel<<<dim3(512), dim3(256), 0, stream>>>(zn, s_part);
    finalize_kernel<<<dim3(1), dim3(1024), 0, stream>>>(s_part, posdot, mask, out);
}